// Round 1
// baseline (2305.217 us; speedup 1.0000x reference)
//
#include <hip/hip_runtime.h>
#include <math.h>

// Problem constants (fixed by setup_inputs)
#define E_N 100000
#define D_N 300
#define R_N 1000
#define T_N 10000
#define K_N 25
#define DP  320      // padded D (multiple of 32)
#define KD  960      // padded 3D
#define NNZ_REL 300000
#define NNZ_ADJ 600000

typedef __attribute__((ext_vector_type(8))) short bf16x8;
typedef __attribute__((ext_vector_type(4))) float f32x4;

__device__ __forceinline__ float bf2f(unsigned short h){
  union{ unsigned int u; float f; } c; c.u = ((unsigned int)h)<<16; return c.f;
}
__device__ __forceinline__ unsigned short f2bf(float f){
  union{ float f; unsigned int u; } c; c.f = f;
  unsigned int u = c.u + 0x7FFFu + ((c.u>>16)&1u);   // RNE
  return (unsigned short)(u>>16);
}

// ---------------- workspace layout (bytes) ----------------
// activations: one 192MB region; embb->h->hg1->node reuse [0,64MB) in place
// (safe: GEMM blocks own full N-width, so each A-row is read only by the
//  block that writes it, and epilogue runs after the final k-loop barrier)
static constexpr size_t OFF_EMBB  = 0;                         // E*320*2 = 64MB (emb/h/hg1/node)
static constexpr size_t OFF_NBB   = 64000000;                  // E*640*2 = 128MB (nb)
static constexpr size_t OFF_HWB   = OFF_NBB;                   // 64MB (h@W alias, nb dead)
static constexpr size_t OFF_GCNB  = OFF_NBB + 64000000;        // 64MB
static constexpr size_t OFF_RFWD  = 192000000;                 // R*600*4
static constexpr size_t OFF_WTKG  = OFF_RFWD + 2400000;        // [320,320] bf16 transposed
static constexpr size_t OFF_WTW1  = OFF_WTKG + 204800;
static constexpr size_t OFF_WTW2  = OFF_WTW1 + 204800;
static constexpr size_t OFF_WTDN  = OFF_WTW2 + 204800;         // [320,960] bf16 transposed
static constexpr size_t OFF_BIASP = OFF_WTDN + 614400;         // 320 f32
static constexpr size_t OFF_BGP   = OFF_BIASP + 1280;
static constexpr size_t OFF_PTRHR = OFF_BGP + 1280;
static constexpr size_t OFF_PTRTR = OFF_PTRHR + 4096;
static constexpr size_t OFF_PTRER = OFF_PTRTR + 4096;
static constexpr size_t OFF_PTRADJ= OFF_PTRER + 400896;
static constexpr size_t OFF_CURHR = OFF_PTRADJ + 400896;       // cursors contiguous: 1 memset
static constexpr size_t OFF_CURTR = OFF_CURHR + 4096;
static constexpr size_t OFF_CURER = OFF_CURTR + 4096;
static constexpr size_t OFF_CURADJ= OFF_CURER + 400896;
static constexpr size_t SZ_CURALL = 4096+4096+400896+400896;
static constexpr size_t OFF_SCHR  = OFF_CURADJ + 400896;
static constexpr size_t OFF_SVHR  = OFF_SCHR + 1200000;
static constexpr size_t OFF_SCTR  = OFF_SVHR + 1200000;
static constexpr size_t OFF_SVTR  = OFF_SCTR + 1200000;
static constexpr size_t OFF_SCER  = OFF_SVTR + 1200000;
static constexpr size_t OFF_SVER  = OFF_SCER + 1200000;
static constexpr size_t OFF_SCADJ = OFF_SVER + 1200000;
static constexpr size_t OFF_SVADJ = OFF_SCADJ + 2400000;
static constexpr size_t OFF_DM    = OFF_SVADJ + 2400000;
static constexpr size_t OFF_PART  = OFF_DM + 40000;
// total ~209.3 MB

// ---------------- weight prep ----------------
// Wt[n][k] = W[k][n], bf16, zero-padded to 320x320
__global__ void k_prep_sq(const float* kg, const float* w1, const float* w2,
                          unsigned short* wtKG, unsigned short* wtW1, unsigned short* wtW2){
  int n = blockIdx.x, which = blockIdx.y, k = threadIdx.x;
  const float* src = which==0 ? kg : (which==1 ? w1 : w2);
  unsigned short* dst = which==0 ? wtKG : (which==1 ? wtW1 : wtW2);
  float v = (n < D_N && k < D_N) ? src[k*D_N + n] : 0.f;
  dst[(size_t)n*DP + k] = f2bf(v);
}

// DenseP_t[n][k]: k<300 -> Dense[k][n] (emb part); 320<=k<920 -> Dense[k-20][n] (nb part)
__global__ void k_prep_dense(const float* dn, unsigned short* wt){
  int n = blockIdx.x, t = threadIdx.x;
  for(int k=t; k<KD; k+=320){
    int ko = (k < D_N) ? k : ((k >= DP && k < 920) ? k-20 : -1);
    float v = (n < D_N && ko >= 0) ? dn[(size_t)ko*D_N + n] : 0.f;
    wt[(size_t)n*KD + k] = f2bf(v);
  }
}

__global__ void k_prep_bias(const float* bias, const float* bg, float* biasP, float* bgP){
  int t = threadIdx.x;
  biasP[t] = (t < D_N) ? bias[t] : 0.f;
  bgP[t]   = (t < D_N) ? bg[t]   : 0.f;
}

// ---------------- emb normalize -> bf16 padded ----------------
__global__ void k_normalize(const float* w, unsigned short* embb){
  int e = blockIdx.x, t = threadIdx.x;            // 256 threads
  __shared__ float s[256];
  float x0 = w[(size_t)e*D_N + t];
  float x1 = (t+256 < D_N) ? w[(size_t)e*D_N + t + 256] : 0.f;
  s[t] = x0*x0 + x1*x1;
  __syncthreads();
  for(int off=128; off>0; off>>=1){ if(t<off) s[t]+=s[t+off]; __syncthreads(); }
  float rn = rsqrtf(s[0]);
  embb[(size_t)e*DP + t] = f2bf(x0*rn);
  int t2 = t+256;
  if(t2 < DP) embb[(size_t)e*DP + t2] = (t2 < D_N) ? f2bf(x1*rn) : (unsigned short)0;
}

// ---------------- CSR build (counting sort), fused over 4 matrices ----------------
__global__ void k_count(const int* hr, const int* tr, const int* er, const int* ad,
                        int* cHR, int* cTR, int* cER, int* cAD){
  int i = blockIdx.x*256 + threadIdx.x;
  if(i < 300000)       atomicAdd(&cHR[hr[i]], 1);
  else if(i < 600000)  atomicAdd(&cTR[tr[i-300000]], 1);
  else if(i < 900000)  atomicAdd(&cER[er[i-600000]], 1);
  else if(i < 1500000) atomicAdd(&cAD[ad[i-900000]], 1);
}

// block b scans matrix b: exclusive scan of cnt[0..n) -> ptr[0..n]; cnt becomes cursor copy
__global__ void k_scan4(int* cHR, int* cTR, int* cER, int* cAD,
                        int* pHR, int* pTR, int* pER, int* pAD){
  int* cnt; int* ptr; int n;
  if(blockIdx.x==0){ cnt=cHR; ptr=pHR; n=R_N; }
  else if(blockIdx.x==1){ cnt=cTR; ptr=pTR; n=R_N; }
  else if(blockIdx.x==2){ cnt=cER; ptr=pER; n=E_N; }
  else { cnt=cAD; ptr=pAD; n=E_N; }
  __shared__ int s[1024];
  __shared__ int carryS;
  int t = threadIdx.x;
  if(t==0) carryS = 0;
  __syncthreads();
  for(int base=0; base<=n; base+=1024){
    int i = base + t;
    int c = (i<n) ? cnt[i] : 0;
    s[t] = c; __syncthreads();
    for(int off=1; off<1024; off<<=1){
      int v = (t>=off) ? s[t-off] : 0;
      __syncthreads();
      s[t] += v;
      __syncthreads();
    }
    int excl = carryS + s[t] - c;
    if(i<=n) ptr[i] = excl;
    if(i<n)  cnt[i] = excl;   // cursor
    __syncthreads();
    if(t==0) carryS += s[1023];
    __syncthreads();
  }
}

__global__ void k_scatter(const int* hr_r, const int* hr_c, const float* hr_v,
                          const int* tr_r, const int* tr_c, const float* tr_v,
                          const int* er_r, const int* er_c, const float* er_v,
                          const int* ad_r, const int* ad_c, const float* ad_v,
                          int* cHR, int* cTR, int* cER, int* cAD,
                          int* scHR, float* svHR, int* scTR, float* svTR,
                          int* scER, float* svER, int* scAD, float* svAD){
  int i = blockIdx.x*256 + threadIdx.x;
  if(i < 300000){ int p=atomicAdd(&cHR[hr_r[i]],1); scHR[p]=hr_c[i]; svHR[p]=hr_v[i]; }
  else if(i < 600000){ int j=i-300000; int p=atomicAdd(&cTR[tr_r[j]],1); scTR[p]=tr_c[j]; svTR[p]=tr_v[j]; }
  else if(i < 900000){ int j=i-600000; int p=atomicAdd(&cER[er_r[j]],1); scER[p]=er_c[j]; svER[p]=er_v[j]; }
  else if(i < 1500000){ int j=i-900000; int p=atomicAdd(&cAD[ad_r[j]],1); scAD[p]=ad_c[j]; svAD[p]=ad_v[j]; }
}

// ---------------- spmm's (CSR per-row, no atomics) ----------------
// r_fwd[r][off..off+300) = sum val * emb[col]
__global__ void k_spmm_rel(const int* ptr, const int* scol, const float* sval,
                           const unsigned short* embb, float* rfwd, int off){
  int r = blockIdx.x, t = threadIdx.x;             // 320 threads
  int b = ptr[r], e2 = ptr[r+1];
  float acc = 0.f;
  for(int j=b; j<e2; j++){
    int c = scol[j]; float v = sval[j];
    if(t < D_N) acc += v * bf2f(embb[(size_t)c*DP + t]);
  }
  if(t < D_N) rfwd[(size_t)r*600 + off + t] = acc;
}

// nb[e][0..600) = sum val * (+/-)r_fwd[col mod R]; write bf16 padded to 640
__global__ void k_spmm_er(const int* ptr, const int* scol, const float* sval,
                          const float* rfwd, unsigned short* nbb){
  int e = blockIdx.x, t = threadIdx.x;             // 320 threads
  int b = ptr[e], en = ptr[e+1];
  float a0 = 0.f, a1 = 0.f;
  int t2 = t + 320;
  for(int j=b; j<en; j++){
    int c = scol[j]; float v = sval[j];
    float sgn = 1.f; int cp = c;
    if(c >= R_N){ cp = c - R_N; sgn = -1.f; }
    float vv = v * sgn;
    a0 += vv * rfwd[(size_t)cp*600 + t];
    if(t2 < 600) a1 += vv * rfwd[(size_t)cp*600 + t2];
  }
  nbb[(size_t)e*640 + t]  = f2bf(a0);
  nbb[(size_t)e*640 + t2] = (t2 < 600) ? f2bf(a1) : (unsigned short)0;
}

// gcn[e] = relu(sum val * x[col]), bf16 in/out, padded cols stay 0
__global__ void k_spmm_adj(const int* ptr, const int* scol, const float* sval,
                           const unsigned short* xin, unsigned short* out){
  int e = blockIdx.x, t = threadIdx.x;             // 320 threads
  int b = ptr[e], en = ptr[e+1];
  float acc = 0.f;
  for(int j=b; j<en; j++){
    int c = scol[j]; float v = sval[j];
    acc += v * bf2f(xin[(size_t)c*DP + t]);
  }
  out[(size_t)e*DP + t] = f2bf(fmaxf(acc, 0.f));
}

// ---------------- MFMA GEMM: C[E,320] = A[E,Kp] @ B[Kp,320] + epilogue ----------------
// BM=64, BN=320 (full width -> per-row in-place output is safe), BK=32.
// 4 waves; wave w computes rows 0..63 x cols [80w,80w+80): 4 m-frags x 5 n-frags.
// mode 0: out = bf16(c)                                  (h@W1, hg1@W2)
// mode 1: out = bf16( res + relu(c + biasP) )            (Dense fusion, res=emb)
// mode 2: tg = sigmoid(c + biasP); out = bf16(tg*gcn + (1-tg)*res)  (highway)
#define BM 64
#define BK 32
#define BKP 40   // +8 bf16 pad: 80B rows, 16B-aligned, <=2-way LDS bank aliasing
__global__ __launch_bounds__(256) void k_gemm(
    const unsigned short* A1,        // [E, DP]
    const unsigned short* A2,        // [E, 640] (Dense only: k>=320), else null
    const unsigned short* __restrict__ Bt,  // [320, Kp]  (B transposed: Bt[n][k])
    int Kp,
    const float* __restrict__ biasP,
    const unsigned short* gcn,
    const unsigned short* res,
    unsigned short* out,
    int mode){
  __shared__ __align__(16) unsigned short As[BM][BKP];
  __shared__ __align__(16) unsigned short Bs[DP][BKP];
  int tid = threadIdx.x;
  int wave = tid >> 6, lane = tid & 63;
  int quad = lane >> 4, l16 = lane & 15;
  int m0 = blockIdx.x * BM;
  f32x4 acc[4][5];
  #pragma unroll
  for(int mi=0; mi<4; mi++)
    #pragma unroll
    for(int ni=0; ni<5; ni++) acc[mi][ni] = (f32x4){0.f,0.f,0.f,0.f};

  for(int k0 = 0; k0 < Kp; k0 += BK){
    // stage A: 64 rows x 32 cols = 512 uint2 chunks
    #pragma unroll
    for(int i=0; i<2; i++){
      int idx = tid + i*256;
      int row = idx >> 3, c4 = (idx & 7) * 4;
      int gr = m0 + row;
      uint2 val = make_uint2(0u, 0u);
      if(gr < E_N){
        int k = k0 + c4;
        const unsigned short* src = (k < DP) ? &A1[(size_t)gr*DP + k]
                                             : &A2[(size_t)gr*640 + (k - DP)];
        val = *(const uint2*)src;
      }
      *(uint2*)&As[row][c4] = val;
    }
    // stage B: 320 rows x 32 cols = 2560 uint2 chunks
    #pragma unroll
    for(int i=0; i<10; i++){
      int idx = tid + i*256;
      int row = idx >> 3, c4 = (idx & 7) * 4;
      uint2 val = *(const uint2*)&Bt[(size_t)row*Kp + k0 + c4];
      *(uint2*)&Bs[row][c4] = val;
    }
    __syncthreads();
    bf16x8 af[4], bfr[5];
    #pragma unroll
    for(int mi=0; mi<4; mi++)
      af[mi] = *(const bf16x8*)&As[mi*16 + l16][quad*8];
    #pragma unroll
    for(int ni=0; ni<5; ni++)
      bfr[ni] = *(const bf16x8*)&Bs[wave*80 + ni*16 + l16][quad*8];
    #pragma unroll
    for(int mi=0; mi<4; mi++)
      #pragma unroll
      for(int ni=0; ni<5; ni++)
        acc[mi][ni] = __builtin_amdgcn_mfma_f32_16x16x32_bf16(af[mi], bfr[ni], acc[mi][ni], 0, 0, 0);
    __syncthreads();
  }

  // epilogue: C/D layout col=lane&15, row=quad*4+i
  #pragma unroll
  for(int mi=0; mi<4; mi++){
    #pragma unroll
    for(int ni=0; ni<5; ni++){
      int col = wave*80 + ni*16 + l16;
      #pragma unroll
      for(int i=0; i<4; i++){
        int row = m0 + mi*16 + quad*4 + i;
        if(row >= E_N) continue;
        size_t idx = (size_t)row*DP + col;
        float c = acc[mi][ni][i];
        float o;
        if(mode == 0){
          o = c;
        } else if(mode == 1){
          o = bf2f(res[idx]) + fmaxf(c + biasP[col], 0.f);
        } else {
          float tg = 1.f / (1.f + expf(-(c + biasP[col])));
          o = tg * bf2f(gcn[idx]) + (1.f - tg) * bf2f(res[idx]);
        }
        out[idx] = f2bf(o);
      }
    }
  }
}

// ---------------- loss ----------------
__global__ void k_dm(const unsigned short* node, const int* pl, const int* pr, float* Dm){
  int w = threadIdx.x >> 6, lane = threadIdx.x & 63;
  int t = blockIdx.x*4 + w;
  size_t lb = (size_t)pl[t]*DP, rb = (size_t)pr[t]*DP;
  float s = 0.f;
  #pragma unroll
  for(int i=0; i<5; i++){
    int d = lane + 64*i;
    s += fabsf(bf2f(node[lb+d]) - bf2f(node[rb+d]));
  }
  #pragma unroll
  for(int off=32; off; off>>=1) s += __shfl_xor(s, off);
  if(lane==0) Dm[t] = s + 1.0f;   // + GAMMA
}

__global__ void k_loss(const unsigned short* node, const int* pl, const int* pr,
                       const int* nr, const int* nl, const float* mask,
                       const float* Dm, float* part){
  int t = blockIdx.x;
  int w = threadIdx.x >> 6, lane = threadIdx.x & 63;
  __shared__ float wsum[4];
  size_t lb = (size_t)pl[t]*DP, rb = (size_t)pr[t]*DP;
  float lv[5], rv[5];
  #pragma unroll
  for(int i=0; i<5; i++){
    int d = lane + 64*i;
    lv[i] = bf2f(node[lb+d]);
    rv[i] = bf2f(node[rb+d]);
  }
  float dm = Dm[t];
  float local = 0.f;
  for(int k=w; k<K_N; k+=4){
    size_t nrb = (size_t)nr[t*K_N+k]*DP, nlb = (size_t)nl[t*K_N+k]*DP;
    float s1 = 0.f, s2 = 0.f;
    #pragma unroll
    for(int i=0; i<5; i++){
      int d = lane + 64*i;
      s1 += fabsf(lv[i] - bf2f(node[nrb+d]));
      s2 += fabsf(bf2f(node[nlb+d]) - rv[i]);
    }
    #pragma unroll
    for(int off=32; off; off>>=1){ s1 += __shfl_xor(s1, off); s2 += __shfl_xor(s2, off); }
    if(lane==0){
      float m = mask[t*K_N+k];
      local += (fmaxf(dm - s1, 0.f) + fmaxf(dm - s2, 0.f)) * m;
    }
  }
  if(lane==0) wsum[w] = local;
  __syncthreads();
  if(threadIdx.x==0) part[t] = wsum[0]+wsum[1]+wsum[2]+wsum[3];
}

__global__ void k_reduce(const float* part, float* out){
  __shared__ float s[256];
  int t = threadIdx.x;
  float a = 0.f;
  for(int i=t; i<T_N; i+=256) a += part[i];
  s[t] = a; __syncthreads();
  for(int off=128; off; off>>=1){ if(t<off) s[t]+=s[t+off]; __syncthreads(); }
  if(t==0) out[0] = s[0]*0.5f;
}

// ---------------- driver ----------------
extern "C" void kernel_launch(void* const* d_in, const int* in_sizes, int n_in,
                              void* d_out, int out_size, void* d_ws, size_t ws_size,
                              hipStream_t stream){
  const float* Wemb = (const float*)d_in[0];
  const float* KG   = (const float*)d_in[1];
  const float* BG   = (const float*)d_in[2];
  const float* W1   = (const float*)d_in[3];
  const float* W2   = (const float*)d_in[4];
  const float* DN   = (const float*)d_in[5];
  const float* BI   = (const float*)d_in[6];
  const int* HRr = (const int*)d_in[7];  const int* HRc = (const int*)d_in[8];  const float* HRv = (const float*)d_in[9];
  const int* TRr = (const int*)d_in[10]; const int* TRc = (const int*)d_in[11]; const float* TRv = (const float*)d_in[12];
  const int* ERr = (const int*)d_in[13]; const int* ERc = (const int*)d_in[14]; const float* ERv = (const float*)d_in[15];
  const int* ADr = (const int*)d_in[16]; const int* ADc = (const int*)d_in[17]; const float* ADv = (const float*)d_in[18];
  const int* PL = (const int*)d_in[19]; const int* PR = (const int*)d_in[20];
  const int* NR = (const int*)d_in[21]; const int* NL = (const int*)d_in[22];
  const float* MASK = (const float*)d_in[23];
  char* ws = (char*)d_ws;

  unsigned short* embb = (unsigned short*)(ws + OFF_EMBB);  // then h, hg1, node (in place)
  unsigned short* nbb  = (unsigned short*)(ws + OFF_NBB);
  unsigned short* hwb  = (unsigned short*)(ws + OFF_HWB);
  unsigned short* gcnb = (unsigned short*)(ws + OFF_GCNB);
  float* rfwd  = (float*)(ws + OFF_RFWD);
  unsigned short* wtKG = (unsigned short*)(ws + OFF_WTKG);
  unsigned short* wtW1 = (unsigned short*)(ws + OFF_WTW1);
  unsigned short* wtW2 = (unsigned short*)(ws + OFF_WTW2);
  unsigned short* wtDN = (unsigned short*)(ws + OFF_WTDN);
  float* biasP = (float*)(ws + OFF_BIASP);
  float* bgP   = (float*)(ws + OFF_BGP);
  int* pHR = (int*)(ws + OFF_PTRHR); int* pTR = (int*)(ws + OFF_PTRTR);
  int* pER = (int*)(ws + OFF_PTRER); int* pAD = (int*)(ws + OFF_PTRADJ);
  int* cHR = (int*)(ws + OFF_CURHR); int* cTR = (int*)(ws + OFF_CURTR);
  int* cER = (int*)(ws + OFF_CURER); int* cAD = (int*)(ws + OFF_CURADJ);
  int* scHR = (int*)(ws + OFF_SCHR); float* svHR = (float*)(ws + OFF_SVHR);
  int* scTR = (int*)(ws + OFF_SCTR); float* svTR = (float*)(ws + OFF_SVTR);
  int* scER = (int*)(ws + OFF_SCER); float* svER = (float*)(ws + OFF_SVER);
  int* scAD = (int*)(ws + OFF_SCADJ); float* svAD = (float*)(ws + OFF_SVADJ);
  float* Dm   = (float*)(ws + OFF_DM);
  float* part = (float*)(ws + OFF_PART);

  (void)hipMemsetAsync(ws + OFF_CURHR, 0, SZ_CURALL, stream);

  k_prep_sq<<<dim3(320,3), 320, 0, stream>>>(KG, W1, W2, wtKG, wtW1, wtW2);
  k_prep_dense<<<320, 320, 0, stream>>>(DN, wtDN);
  k_prep_bias<<<1, 320, 0, stream>>>(BI, BG, biasP, bgP);
  k_normalize<<<E_N, 256, 0, stream>>>(Wemb, embb);

  k_count<<<5860, 256, 0, stream>>>(HRr, TRr, ERr, ADr, cHR, cTR, cER, cAD);
  k_scan4<<<4, 1024, 0, stream>>>(cHR, cTR, cER, cAD, pHR, pTR, pER, pAD);
  k_scatter<<<5860, 256, 0, stream>>>(HRr,HRc,HRv, TRr,TRc,TRv, ERr,ERc,ERv, ADr,ADc,ADv,
                                      cHR,cTR,cER,cAD, scHR,svHR, scTR,svTR, scER,svER, scAD,svAD);

  k_spmm_rel<<<R_N, 320, 0, stream>>>(pHR, scHR, svHR, embb, rfwd, 0);
  k_spmm_rel<<<R_N, 320, 0, stream>>>(pTR, scTR, svTR, embb, rfwd, 300);
  k_spmm_er <<<E_N, 320, 0, stream>>>(pER, scER, svER, rfwd, nbb);

  const int GB = (E_N + BM - 1) / BM;  // 1563
  // h = emb + relu([emb|nb] @ Dense + Bias)   (in place over embb)
  k_gemm<<<GB, 256, 0, stream>>>(embb, nbb, wtDN, KD, biasP, nullptr, embb, embb, 1);
  // gcn1 = relu(spmm(adj, h@W1))
  k_gemm<<<GB, 256, 0, stream>>>(embb, nullptr, wtW1, DP, nullptr, nullptr, nullptr, hwb, 0);
  k_spmm_adj<<<E_N, 320, 0, stream>>>(pAD, scAD, svAD, hwb, gcnb);
  // hg1 = highway(h, gcn1)   (in place)
  k_gemm<<<GB, 256, 0, stream>>>(embb, nullptr, wtKG, DP, bgP, gcnb, embb, embb, 2);
  // gcn2 = relu(spmm(adj, hg1@W2))
  k_gemm<<<GB, 256, 0, stream>>>(embb, nullptr, wtW2, DP, nullptr, nullptr, nullptr, hwb, 0);
  k_spmm_adj<<<E_N, 320, 0, stream>>>(pAD, scAD, svAD, hwb, gcnb);
  // node = highway(hg1, gcn2)   (in place)
  k_gemm<<<GB, 256, 0, stream>>>(embb, nullptr, wtKG, DP, bgP, gcnb, embb, embb, 2);

  k_dm<<<T_N/4, 256, 0, stream>>>(embb, PL, PR, Dm);
  k_loss<<<T_N, 256, 0, stream>>>(embb, PL, PR, NR, NL, MASK, Dm, part);
  k_reduce<<<1, 256, 0, stream>>>(part, (float*)d_out);
}

// Round 2
// 1808.799 us; speedup vs baseline: 1.2744x; 1.2744x over previous
//
#include <hip/hip_runtime.h>
#include <math.h>

// Problem constants (fixed by setup_inputs)
#define E_N 100000
#define D_N 300
#define R_N 1000
#define T_N 10000
#define K_N 25
#define DP  320      // padded D (multiple of 32)
#define KD  960      // padded 3D

typedef __attribute__((ext_vector_type(8))) short bf16x8;
typedef __attribute__((ext_vector_type(4))) float f32x4;

__device__ __forceinline__ float bf2f(unsigned short h){
  union{ unsigned int u; float f; } c; c.u = ((unsigned int)h)<<16; return c.f;
}
__device__ __forceinline__ unsigned short f2bf(float f){
  union{ float f; unsigned int u; } c; c.f = f;
  unsigned int u = c.u + 0x7FFFu + ((c.u>>16)&1u);   // RNE
  return (unsigned short)(u>>16);
}

// ---------------- workspace layout (bytes) ----------------
static constexpr size_t OFF_EMBB  = 0;                         // E*320*2 = 64MB (emb/h/hg1/node, in place)
static constexpr size_t OFF_NBB   = 64000000;                  // E*640*2 = 128MB (nb)
static constexpr size_t OFF_HWB   = OFF_NBB;                   // 64MB (h@W alias, nb dead by then)
static constexpr size_t OFF_GCNB  = OFF_NBB + 64000000;        // 64MB
static constexpr size_t OFF_RFWD  = 192000000;                 // R*640*2 bf16 = 1.28MB
static constexpr size_t OFF_WTKG  = OFF_RFWD + 2400000;
static constexpr size_t OFF_WTW1  = OFF_WTKG + 204800;
static constexpr size_t OFF_WTW2  = OFF_WTW1 + 204800;
static constexpr size_t OFF_WTDN  = OFF_WTW2 + 204800;         // [320,960] bf16 transposed
static constexpr size_t OFF_BIASP = OFF_WTDN + 614400;
static constexpr size_t OFF_BGP   = OFF_BIASP + 1280;
static constexpr size_t OFF_PTRHR = OFF_BGP + 1280;
static constexpr size_t OFF_PTRTR = OFF_PTRHR + 4096;
static constexpr size_t OFF_PTRER = OFF_PTRTR + 4096;
static constexpr size_t OFF_PTRADJ= OFF_PTRER + 400896;
static constexpr size_t OFF_CURHR = OFF_PTRADJ + 400896;       // cursors contiguous: 1 memset
static constexpr size_t OFF_CURTR = OFF_CURHR + 4096;
static constexpr size_t OFF_CURER = OFF_CURTR + 4096;
static constexpr size_t OFF_CURADJ= OFF_CURER + 400896;
static constexpr size_t SZ_CURALL = 4096+4096+400896+400896;
static constexpr size_t OFF_SCHR  = OFF_CURADJ + 400896;
static constexpr size_t OFF_SVHR  = OFF_SCHR + 1200000;
static constexpr size_t OFF_SCTR  = OFF_SVHR + 1200000;
static constexpr size_t OFF_SVTR  = OFF_SCTR + 1200000;
static constexpr size_t OFF_SCER  = OFF_SVTR + 1200000;
static constexpr size_t OFF_SVER  = OFF_SCER + 1200000;
static constexpr size_t OFF_SCADJ = OFF_SVER + 1200000;
static constexpr size_t OFF_SVADJ = OFF_SCADJ + 2400000;
static constexpr size_t OFF_DM    = OFF_SVADJ + 2400000;
static constexpr size_t OFF_PART  = OFF_DM + 40000;
static constexpr size_t OFF_BSUM  = OFF_PART + 40000;          // 256 ints
// total ~209.3 MB

// ---------------- weight prep ----------------
__global__ void k_prep_sq(const float* kg, const float* w1, const float* w2,
                          unsigned short* wtKG, unsigned short* wtW1, unsigned short* wtW2){
  int n = blockIdx.x, which = blockIdx.y, k = threadIdx.x;
  const float* src = which==0 ? kg : (which==1 ? w1 : w2);
  unsigned short* dst = which==0 ? wtKG : (which==1 ? wtW1 : wtW2);
  float v = (n < D_N && k < D_N) ? src[k*D_N + n] : 0.f;
  dst[(size_t)n*DP + k] = f2bf(v);
}

// DenseP_t[n][k]: k<300 -> Dense[k][n]; 320<=k<920 -> Dense[k-20][n]; else 0
__global__ void k_prep_dense(const float* dn, unsigned short* wt){
  int n = blockIdx.x, t = threadIdx.x;
  for(int k=t; k<KD; k+=320){
    int ko = (k < D_N) ? k : ((k >= DP && k < 920) ? k-20 : -1);
    float v = (n < D_N && ko >= 0) ? dn[(size_t)ko*D_N + n] : 0.f;
    wt[(size_t)n*KD + k] = f2bf(v);
  }
}

__global__ void k_prep_bias(const float* bias, const float* bg, float* biasP, float* bgP){
  int t = threadIdx.x;
  biasP[t] = (t < D_N) ? bias[t] : 0.f;
  bgP[t]   = (t < D_N) ? bg[t]   : 0.f;
}

// ---------------- emb normalize -> bf16 padded ----------------
__global__ void k_normalize(const float* w, unsigned short* embb){
  int e = blockIdx.x, t = threadIdx.x;            // 256 threads
  __shared__ float s[256];
  float x0 = w[(size_t)e*D_N + t];
  float x1 = (t+256 < D_N) ? w[(size_t)e*D_N + t + 256] : 0.f;
  s[t] = x0*x0 + x1*x1;
  __syncthreads();
  for(int off=128; off>0; off>>=1){ if(t<off) s[t]+=s[t+off]; __syncthreads(); }
  float rn = rsqrtf(s[0]);
  embb[(size_t)e*DP + t] = f2bf(x0*rn);
  int t2 = t+256;
  if(t2 < DP) embb[(size_t)e*DP + t2] = (t2 < D_N) ? f2bf(x1*rn) : (unsigned short)0;
}

// ---------------- CSR build (counting sort) ----------------
__global__ void k_count(const int* hr, const int* tr, const int* er, const int* ad,
                        int* cHR, int* cTR, int* cER, int* cAD){
  int i = blockIdx.x*256 + threadIdx.x;
  if(i < 300000)       atomicAdd(&cHR[hr[i]], 1);
  else if(i < 600000)  atomicAdd(&cTR[tr[i-300000]], 1);
  else if(i < 900000)  atomicAdd(&cER[er[i-600000]], 1);
  else if(i < 1500000) atomicAdd(&cAD[ad[i-900000]], 1);
}

// 1 block: scan HR and TR (n=1000 each); cnt becomes cursor
__global__ void k_scan_small(int* cHR, int* cTR, int* pHR, int* pTR){
  __shared__ int s[1024];
  int t = threadIdx.x;
  for(int w=0; w<2; w++){
    int* cnt = w ? cTR : cHR; int* ptr = w ? pTR : pHR;
    int c = (t < R_N) ? cnt[t] : 0;
    s[t] = c; __syncthreads();
    for(int off=1; off<1024; off<<=1){
      int v = (t>=off) ? s[t-off] : 0; __syncthreads();
      s[t] += v; __syncthreads();
    }
    int excl = s[t] - c;
    if(t < R_N){ ptr[t] = excl; cnt[t] = excl; }
    if(t == R_N-1) ptr[R_N] = s[t];
    __syncthreads();
  }
}

// phase 1: per-1024-chunk exclusive scan of ER/ADJ counts; chunk totals to bsum
__global__ void k_scan_part(const int* cER, const int* cAD, int* pER, int* pAD, int* bsum){
  int which = blockIdx.y;
  const int* cnt = which ? cAD : cER;
  int* ptr = which ? pAD : pER;
  __shared__ int s[1024];
  int g = blockIdx.x, t = threadIdx.x, i = g*1024 + t;
  int c = (i < E_N) ? cnt[i] : 0;
  s[t] = c; __syncthreads();
  for(int off=1; off<1024; off<<=1){
    int v = (t>=off) ? s[t-off] : 0; __syncthreads();
    s[t] += v; __syncthreads();
  }
  if(i < E_N) ptr[i] = s[t] - c;
  if(t == 1023) bsum[which*128 + g] = s[1023];
}

// phase 2: 1 block scans the 98 chunk totals per matrix; writes ptr[E_N]=total
__global__ void k_scan_mid(int* bsum, int* pER, int* pAD){
  __shared__ int s[128];
  int t = threadIdx.x;
  for(int w=0; w<2; w++){
    int v = (t < 98) ? bsum[w*128 + t] : 0;
    s[t] = v; __syncthreads();
    for(int off=1; off<128; off<<=1){
      int u = (t>=off) ? s[t-off] : 0; __syncthreads();
      s[t] += u; __syncthreads();
    }
    if(t < 98) bsum[w*128 + t] = s[t] - v;
    if(t == 97){ int* p = w ? pAD : pER; p[E_N] = s[97]; }
    __syncthreads();
  }
}

// phase 3: add chunk offsets; write final ptr + cursor (cursor aliases count array)
__global__ void k_scan_add(const int* bsum, int* pER, int* pAD, int* curER, int* curAD){
  int which = blockIdx.y;
  int* ptr = which ? pAD : pER;
  int* cur = which ? curAD : curER;
  int g = blockIdx.x, i = g*1024 + threadIdx.x;
  if(i < E_N){ int v = ptr[i] + bsum[which*128 + g]; ptr[i] = v; cur[i] = v; }
}

__global__ void k_scatter(const int* hr_r, const int* hr_c, const float* hr_v,
                          const int* tr_r, const int* tr_c, const float* tr_v,
                          const int* er_r, const int* er_c, const float* er_v,
                          const int* ad_r, const int* ad_c, const float* ad_v,
                          int* cHR, int* cTR, int* cER, int* cAD,
                          int* scHR, float* svHR, int* scTR, float* svTR,
                          int* scER, float* svER, int* scAD, float* svAD){
  int i = blockIdx.x*256 + threadIdx.x;
  if(i < 300000){ int p=atomicAdd(&cHR[hr_r[i]],1); scHR[p]=hr_c[i]; svHR[p]=hr_v[i]; }
  else if(i < 600000){ int j=i-300000; int p=atomicAdd(&cTR[tr_r[j]],1); scTR[p]=tr_c[j]; svTR[p]=tr_v[j]; }
  else if(i < 900000){ int j=i-600000; int p=atomicAdd(&cER[er_r[j]],1); scER[p]=er_c[j]; svER[p]=er_v[j]; }
  else if(i < 1500000){ int j=i-900000; int p=atomicAdd(&cAD[ad_r[j]],1); scAD[p]=ad_c[j]; svAD[p]=ad_v[j]; }
}

// ---------------- spmm's (CSR per-row, no atomics) ----------------
// rfwdb[r][off..off+300) bf16 = sum val * emb[col]; wave-per-(row,half), 4B packed lanes
__global__ __launch_bounds__(256) void k_spmm_rel(
    const int* __restrict__ ptr, const int* __restrict__ scol, const float* __restrict__ sval,
    const unsigned short* __restrict__ embb, unsigned short* __restrict__ rfwdb, int off){
  int w = threadIdx.x >> 6, lane = threadIdx.x & 63;
  int r = blockIdx.x*2 + (w>>1);
  int half = w & 1;
  int elem = half*160 + 4*lane;                 // source elem within [0,300)
  bool act = (lane < 40) && (elem < 300);
  int b = ptr[r], e2 = ptr[r+1];
  float a0=0.f, a1=0.f, a2=0.f, a3=0.f;
  if(act){
    const unsigned short* base = embb + elem;
    int j = b;
    for(; j+4 <= e2; j += 4){
      int c0=scol[j], c1=scol[j+1], c2=scol[j+2], c3=scol[j+3];
      float v0=sval[j], v1=sval[j+1], v2=sval[j+2], v3=sval[j+3];
      uint2 x0 = *(const uint2*)(base + (size_t)c0*DP);
      uint2 x1 = *(const uint2*)(base + (size_t)c1*DP);
      uint2 x2 = *(const uint2*)(base + (size_t)c2*DP);
      uint2 x3 = *(const uint2*)(base + (size_t)c3*DP);
      a0 += v0*bf2f(x0.x&0xFFFF) + v1*bf2f(x1.x&0xFFFF) + v2*bf2f(x2.x&0xFFFF) + v3*bf2f(x3.x&0xFFFF);
      a1 += v0*bf2f(x0.x>>16)    + v1*bf2f(x1.x>>16)    + v2*bf2f(x2.x>>16)    + v3*bf2f(x3.x>>16);
      a2 += v0*bf2f(x0.y&0xFFFF) + v1*bf2f(x1.y&0xFFFF) + v2*bf2f(x2.y&0xFFFF) + v3*bf2f(x3.y&0xFFFF);
      a3 += v0*bf2f(x0.y>>16)    + v1*bf2f(x1.y>>16)    + v2*bf2f(x2.y>>16)    + v3*bf2f(x3.y>>16);
    }
    for(; j < e2; j++){
      int c = scol[j]; float v = sval[j];
      uint2 x = *(const uint2*)(base + (size_t)c*DP);
      a0 += v*bf2f(x.x&0xFFFF); a1 += v*bf2f(x.x>>16);
      a2 += v*bf2f(x.y&0xFFFF); a3 += v*bf2f(x.y>>16);
    }
    uint2 o;
    o.x = ((unsigned int)f2bf(a1)<<16) | f2bf(a0);
    o.y = ((unsigned int)f2bf(a3)<<16) | f2bf(a2);
    *(uint2*)&rfwdb[(size_t)r*640 + off + elem] = o;
  }
}

// nb[e][0..640) = sum val * (+/-)rfwdb[col mod R]; 320 threads, 4B packed lanes
__global__ void k_spmm_er(const int* __restrict__ ptr, const int* __restrict__ scol,
                          const float* __restrict__ sval,
                          const unsigned short* __restrict__ rfwdb, unsigned short* __restrict__ nbb){
  int e = blockIdx.x, t = threadIdx.x;           // 320 threads
  int b = ptr[e], en = ptr[e+1];
  float a0 = 0.f, a1 = 0.f;
  const unsigned short* base = rfwdb + 2*t;
  for(int j=b; j<en; j++){
    int c = scol[j]; float v = sval[j];
    int cp = c; float vv = v;
    if(c >= R_N){ cp = c - R_N; vv = -v; }
    unsigned int x = *(const unsigned int*)(base + (size_t)cp*640);
    a0 += vv * bf2f((unsigned short)(x & 0xFFFF));
    a1 += vv * bf2f((unsigned short)(x >> 16));
  }
  unsigned int o = ((unsigned int)f2bf(a1)<<16) | f2bf(a0);
  *(unsigned int*)&nbb[(size_t)e*640 + 2*t] = o;
}

// gcn[e] = relu(sum val * x[col]); wave-per-row, 16B lanes (lanes 0..39)
__global__ __launch_bounds__(256) void k_spmm_adj(
    const int* __restrict__ ptr, const int* __restrict__ scol, const float* __restrict__ sval,
    const unsigned short* __restrict__ xin, unsigned short* __restrict__ out){
  int w = threadIdx.x >> 6, lane = threadIdx.x & 63;
  int e = blockIdx.x*4 + w;
  int b = ptr[e], en = ptr[e+1];
  if(lane < 40){
    float acc[8];
    #pragma unroll
    for(int i=0;i<8;i++) acc[i]=0.f;
    const unsigned short* base = xin + lane*8;
    for(int j=b; j<en; j++){
      int c = scol[j]; float v = sval[j];
      bf16x8 x = *(const bf16x8*)(base + (size_t)c*DP);
      #pragma unroll
      for(int i=0;i<8;i++) acc[i] += v * bf2f((unsigned short)x[i]);
    }
    bf16x8 o;
    #pragma unroll
    for(int i=0;i<8;i++) o[i] = (short)f2bf(fmaxf(acc[i], 0.f));
    *(bf16x8*)&out[(size_t)e*DP + lane*8] = o;
  }
}

// ---------------- MFMA GEMM, LDS-free direct fragments ----------------
// C[E,320] = A[E,K] @ B[K,320] + epilogue. BM=64 rows/block, 4 waves x (4m x 5n) frags.
// A-frag = A[m=l16][k=quad*8+j] (k-contiguous, 16B) loaded straight from global.
// B-frag from Bt[n][k] (k-contiguous) -- L2-resident. No LDS, no k-loop barriers.
// K-loop 1: k in [0,320) from A1. K-loop 2 (Dense only): k in [320,960) from A2[E,640].
// mode 0: out = bf16(c); mode 1: out = bf16(res + relu(c+bias));
// mode 2: tg = sigmoid(c+bias); out = bf16(tg*gcn + (1-tg)*res)
#define BM 64
__global__ __launch_bounds__(256,2) void k_gemm(
    const unsigned short* __restrict__ A1,
    const unsigned short* __restrict__ A2,
    const unsigned short* __restrict__ Bt,
    int KpB,
    const float* __restrict__ biasP,
    const unsigned short* __restrict__ gcn,
    const unsigned short* __restrict__ res,
    unsigned short* __restrict__ out,
    int mode){
  int tid = threadIdx.x;
  int wave = tid >> 6, lane = tid & 63, quad = lane >> 4, l16 = lane & 15;
  int m0 = blockIdx.x * BM;
  const unsigned short* a1p[4];
  const unsigned short* a2p[4];
  const unsigned short* bp[5];
  #pragma unroll
  for(int mi=0; mi<4; mi++){
    int r = m0 + mi*16 + l16; if(r > E_N-1) r = E_N-1;   // clamp: OOB rows read row E-1, discarded at store
    a1p[mi] = A1 + (size_t)r*DP + quad*8;
    a2p[mi] = A2 + (size_t)r*640 + quad*8;
  }
  #pragma unroll
  for(int ni=0; ni<5; ni++)
    bp[ni] = Bt + (size_t)(wave*80 + ni*16 + l16)*KpB + quad*8;

  f32x4 acc[4][5];
  #pragma unroll
  for(int mi=0; mi<4; mi++)
    #pragma unroll
    for(int ni=0; ni<5; ni++) acc[mi][ni] = (f32x4){0.f,0.f,0.f,0.f};

  #pragma unroll 2
  for(int k0=0; k0<DP; k0+=32){
    bf16x8 af[4], bfr[5];
    #pragma unroll
    for(int mi=0; mi<4; mi++) af[mi] = *(const bf16x8*)(a1p[mi] + k0);
    #pragma unroll
    for(int ni=0; ni<5; ni++) bfr[ni] = *(const bf16x8*)(bp[ni] + k0);
    #pragma unroll
    for(int mi=0; mi<4; mi++)
      #pragma unroll
      for(int ni=0; ni<5; ni++)
        acc[mi][ni] = __builtin_amdgcn_mfma_f32_16x16x32_bf16(af[mi], bfr[ni], acc[mi][ni], 0, 0, 0);
  }
  if(A2){
    #pragma unroll 2
    for(int k0=0; k0<640; k0+=32){
      bf16x8 af[4], bfr[5];
      #pragma unroll
      for(int mi=0; mi<4; mi++) af[mi] = *(const bf16x8*)(a2p[mi] + k0);
      #pragma unroll
      for(int ni=0; ni<5; ni++) bfr[ni] = *(const bf16x8*)(bp[ni] + DP + k0);
      #pragma unroll
      for(int mi=0; mi<4; mi++)
        #pragma unroll
        for(int ni=0; ni<5; ni++)
          acc[mi][ni] = __builtin_amdgcn_mfma_f32_16x16x32_bf16(af[mi], bfr[ni], acc[mi][ni], 0, 0, 0);
    }
  }

  __syncthreads();   // in-place safety: all k-loop reads retired before any write
  #pragma unroll
  for(int mi=0; mi<4; mi++){
    #pragma unroll
    for(int ni=0; ni<5; ni++){
      int col = wave*80 + ni*16 + l16;
      #pragma unroll
      for(int i=0; i<4; i++){
        int row = m0 + mi*16 + quad*4 + i;
        if(row >= E_N) continue;
        size_t idx = (size_t)row*DP + col;
        float c = acc[mi][ni][i];
        float o;
        if(mode == 0){
          o = c;
        } else if(mode == 1){
          o = bf2f(res[idx]) + fmaxf(c + biasP[col], 0.f);
        } else {
          float tg = 1.f / (1.f + expf(-(c + biasP[col])));
          o = tg * bf2f(gcn[idx]) + (1.f - tg) * bf2f(res[idx]);
        }
        out[idx] = f2bf(o);
      }
    }
  }
}

// ---------------- loss ----------------
__global__ void k_dm(const unsigned short* node, const int* pl, const int* pr, float* Dm){
  int w = threadIdx.x >> 6, lane = threadIdx.x & 63;
  int t = blockIdx.x*4 + w;
  size_t lb = (size_t)pl[t]*DP, rb = (size_t)pr[t]*DP;
  float s = 0.f;
  #pragma unroll
  for(int i=0; i<5; i++){
    int d = lane + 64*i;
    s += fabsf(bf2f(node[lb+d]) - bf2f(node[rb+d]));
  }
  #pragma unroll
  for(int off=32; off; off>>=1) s += __shfl_xor(s, off);
  if(lane==0) Dm[t] = s + 1.0f;   // + GAMMA
}

__global__ void k_loss(const unsigned short* node, const int* pl, const int* pr,
                       const int* nr, const int* nl, const float* mask,
                       const float* Dm, float* part){
  int t = blockIdx.x;
  int w = threadIdx.x >> 6, lane = threadIdx.x & 63;
  __shared__ float wsum[4];
  size_t lb = (size_t)pl[t]*DP, rb = (size_t)pr[t]*DP;
  float lv[5], rv[5];
  #pragma unroll
  for(int i=0; i<5; i++){
    int d = lane + 64*i;
    lv[i] = bf2f(node[lb+d]);
    rv[i] = bf2f(node[rb+d]);
  }
  float dm = Dm[t];
  float local = 0.f;
  for(int k=w; k<K_N; k+=4){
    size_t nrb = (size_t)nr[t*K_N+k]*DP, nlb = (size_t)nl[t*K_N+k]*DP;
    float s1 = 0.f, s2 = 0.f;
    #pragma unroll
    for(int i=0; i<5; i++){
      int d = lane + 64*i;
      s1 += fabsf(lv[i] - bf2f(node[nrb+d]));
      s2 += fabsf(bf2f(node[nlb+d]) - rv[i]);
    }
    #pragma unroll
    for(int off=32; off; off>>=1){ s1 += __shfl_xor(s1, off); s2 += __shfl_xor(s2, off); }
    if(lane==0){
      float m = mask[t*K_N+k];
      local += (fmaxf(dm - s1, 0.f) + fmaxf(dm - s2, 0.f)) * m;
    }
  }
  if(lane==0) wsum[w] = local;
  __syncthreads();
  if(threadIdx.x==0) part[t] = wsum[0]+wsum[1]+wsum[2]+wsum[3];
}

__global__ void k_reduce(const float* part, float* out){
  __shared__ float s[256];
  int t = threadIdx.x;
  float a = 0.f;
  for(int i=t; i<T_N; i+=256) a += part[i];
  s[t] = a; __syncthreads();
  for(int off=128; off; off>>=1){ if(t<off) s[t]+=s[t+off]; __syncthreads(); }
  if(t==0) out[0] = s[0]*0.5f;
}

// ---------------- driver ----------------
extern "C" void kernel_launch(void* const* d_in, const int* in_sizes, int n_in,
                              void* d_out, int out_size, void* d_ws, size_t ws_size,
                              hipStream_t stream){
  const float* Wemb = (const float*)d_in[0];
  const float* KG   = (const float*)d_in[1];
  const float* BG   = (const float*)d_in[2];
  const float* W1   = (const float*)d_in[3];
  const float* W2   = (const float*)d_in[4];
  const float* DN   = (const float*)d_in[5];
  const float* BI   = (const float*)d_in[6];
  const int* HRr = (const int*)d_in[7];  const int* HRc = (const int*)d_in[8];  const float* HRv = (const float*)d_in[9];
  const int* TRr = (const int*)d_in[10]; const int* TRc = (const int*)d_in[11]; const float* TRv = (const float*)d_in[12];
  const int* ERr = (const int*)d_in[13]; const int* ERc = (const int*)d_in[14]; const float* ERv = (const float*)d_in[15];
  const int* ADr = (const int*)d_in[16]; const int* ADc = (const int*)d_in[17]; const float* ADv = (const float*)d_in[18];
  const int* PL = (const int*)d_in[19]; const int* PR = (const int*)d_in[20];
  const int* NR = (const int*)d_in[21]; const int* NL = (const int*)d_in[22];
  const float* MASK = (const float*)d_in[23];
  char* ws = (char*)d_ws;

  unsigned short* embb = (unsigned short*)(ws + OFF_EMBB);  // then h, hg1, node (in place)
  unsigned short* nbb  = (unsigned short*)(ws + OFF_NBB);
  unsigned short* hwb  = (unsigned short*)(ws + OFF_HWB);
  unsigned short* gcnb = (unsigned short*)(ws + OFF_GCNB);
  unsigned short* rfwdb = (unsigned short*)(ws + OFF_RFWD);
  unsigned short* wtKG = (unsigned short*)(ws + OFF_WTKG);
  unsigned short* wtW1 = (unsigned short*)(ws + OFF_WTW1);
  unsigned short* wtW2 = (unsigned short*)(ws + OFF_WTW2);
  unsigned short* wtDN = (unsigned short*)(ws + OFF_WTDN);
  float* biasP = (float*)(ws + OFF_BIASP);
  float* bgP   = (float*)(ws + OFF_BGP);
  int* pHR = (int*)(ws + OFF_PTRHR); int* pTR = (int*)(ws + OFF_PTRTR);
  int* pER = (int*)(ws + OFF_PTRER); int* pAD = (int*)(ws + OFF_PTRADJ);
  int* cHR = (int*)(ws + OFF_CURHR); int* cTR = (int*)(ws + OFF_CURTR);
  int* cER = (int*)(ws + OFF_CURER); int* cAD = (int*)(ws + OFF_CURADJ);
  int* scHR = (int*)(ws + OFF_SCHR); float* svHR = (float*)(ws + OFF_SVHR);
  int* scTR = (int*)(ws + OFF_SCTR); float* svTR = (float*)(ws + OFF_SVTR);
  int* scER = (int*)(ws + OFF_SCER); float* svER = (float*)(ws + OFF_SVER);
  int* scAD = (int*)(ws + OFF_SCADJ); float* svAD = (float*)(ws + OFF_SVADJ);
  float* Dm   = (float*)(ws + OFF_DM);
  float* part = (float*)(ws + OFF_PART);
  int* bsum   = (int*)(ws + OFF_BSUM);

  (void)hipMemsetAsync(ws + OFF_CURHR, 0, SZ_CURALL, stream);

  k_prep_sq<<<dim3(320,3), 320, 0, stream>>>(KG, W1, W2, wtKG, wtW1, wtW2);
  k_prep_dense<<<320, 320, 0, stream>>>(DN, wtDN);
  k_prep_bias<<<1, 320, 0, stream>>>(BI, BG, biasP, bgP);
  k_normalize<<<E_N, 256, 0, stream>>>(Wemb, embb);

  k_count<<<5860, 256, 0, stream>>>(HRr, TRr, ERr, ADr, cHR, cTR, cER, cAD);
  k_scan_small<<<1, 1024, 0, stream>>>(cHR, cTR, pHR, pTR);
  k_scan_part<<<dim3(98,2), 1024, 0, stream>>>(cER, cAD, pER, pAD, bsum);
  k_scan_mid<<<1, 128, 0, stream>>>(bsum, pER, pAD);
  k_scan_add<<<dim3(98,2), 1024, 0, stream>>>(bsum, pER, pAD, cER, cAD);
  k_scatter<<<5860, 256, 0, stream>>>(HRr,HRc,HRv, TRr,TRc,TRv, ERr,ERc,ERv, ADr,ADc,ADv,
                                      cHR,cTR,cER,cAD, scHR,svHR, scTR,svTR, scER,svER, scAD,svAD);

  k_spmm_rel<<<R_N/2, 256, 0, stream>>>(pHR, scHR, svHR, embb, rfwdb, 0);
  k_spmm_rel<<<R_N/2, 256, 0, stream>>>(pTR, scTR, svTR, embb, rfwdb, 300);
  k_spmm_er <<<E_N, 320, 0, stream>>>(pER, scER, svER, rfwdb, nbb);

  const int GB = (E_N + BM - 1) / BM;  // 1563
  // h = emb + relu([emb|nb] @ Dense + Bias)   (in place over embb)
  k_gemm<<<GB, 256, 0, stream>>>(embb, nbb, wtDN, KD, biasP, nullptr, embb, embb, 1);
  // gcn1 = relu(spmm(adj, h@W1))
  k_gemm<<<GB, 256, 0, stream>>>(embb, nullptr, wtW1, DP, nullptr, nullptr, nullptr, hwb, 0);
  k_spmm_adj<<<E_N/4, 256, 0, stream>>>(pAD, scAD, svAD, hwb, gcnb);
  // hg1 = highway(h, gcn1)   (in place)
  k_gemm<<<GB, 256, 0, stream>>>(embb, nullptr, wtKG, DP, bgP, gcnb, embb, embb, 2);
  // gcn2 = relu(spmm(adj, hg1@W2))
  k_gemm<<<GB, 256, 0, stream>>>(embb, nullptr, wtW2, DP, nullptr, nullptr, nullptr, hwb, 0);
  k_spmm_adj<<<E_N/4, 256, 0, stream>>>(pAD, scAD, svAD, hwb, gcnb);
  // node = highway(hg1, gcn2)   (in place)
  k_gemm<<<GB, 256, 0, stream>>>(embb, nullptr, wtKG, DP, bgP, gcnb, embb, embb, 2);

  k_dm<<<T_N/4, 256, 0, stream>>>(embb, PL, PR, Dm);
  k_loss<<<T_N, 256, 0, stream>>>(embb, PL, PR, NR, NL, MASK, Dm, part);
  k_reduce<<<1, 256, 0, stream>>>(part, (float*)d_out);
}